// Round 6
// baseline (3026.517 us; speedup 1.0000x reference)
//
#include <hip/hip_runtime.h>
#include <hip/hip_bf16.h>

// Neural CDE forward, R6: 16-wave blocks for latency hiding, atomic-free epilogue.
// 256 persistent blocks x 8 rows x 1024 threads (16 waves -> 4 waves/SIMD).
// Layers via mfma_f32_16x16x32_bf16, dup-row A (row = lane&7; C rows 8..15 dup,
// skipped). B-fragments register-loaded from L2 (1KB/instr, unroll 4). L3 tanh
// output -> swizzled bf16 G buffer; separate contraction pass (1 (row,e) per
// thread, 10 bf16 LDS reads). RK4 (3/8) state in registers, 1 elem/thread.

typedef __attribute__((ext_vector_type(4))) float f32x4;
typedef __attribute__((ext_vector_type(8))) short s16x8;

#define N_AG  2048
#define D_IN  10
#define NPTS  46
#define RROWS 8

#define OFF_W0P 0
#define OFF_W1P (128 * 512)
#define OFF_W2P (OFF_W1P + 512 * 512)
#define OFF_W3P (OFF_W2P + 512 * 512)
#define OFF_END (OFF_W3P + 512 * 1280)   // ushorts

__device__ __forceinline__ ushort f2bf(float v) {
  __hip_bfloat16 h = __float2bfloat16(v);
  return *reinterpret_cast<ushort*>(&h);
}
__device__ __forceinline__ float bf2f(ushort u) {
  union { unsigned u; float f; } c; c.u = ((unsigned)u) << 16; return c.f;
}

// Pack W (O x K fp32, row-major) into MFMA B-fragment order (verified R2-R5):
// packed[((ct*KS+ks)*64 + lane)*8 + j] = bf16(W[col][k]),
// col = ct*16 + (lane&15), k = ks*32 + (lane>>4)*8 + j.
__global__ void pack_w(const float* __restrict__ W, ushort* __restrict__ Wp,
                       int O, int K) {
  int idx = blockIdx.x * blockDim.x + threadIdx.x;
  if (idx >= O * K) return;
  int j    = idx & 7;
  int lane = (idx >> 3) & 63;
  int rest = idx >> 9;
  int KS   = K >> 5;
  int ks   = rest % KS;
  int ct   = rest / KS;
  int col  = (ct << 4) + (lane & 15);
  int k    = (ks << 5) + ((lane >> 4) << 3) + j;
  Wp[idx]  = f2bf(W[col * K + k]);
}

// Natural cubic spline derivative table (verified R1-R5).
__global__ void spline_dx_k(const float* __restrict__ x, float* __restrict__ dX) {
  int idx = blockIdx.x * blockDim.x + threadIdx.x;
  if (idx >= N_AG * D_IN) return;
  int n = idx / D_IN;
  int d = idx - n * D_IN;

  float xv[16];
#pragma unroll
  for (int t = 0; t < 16; ++t) xv[t] = x[n * 160 + t * 10 + d];

  float cp[15], dp[15], M[16];
  {
    float rhs = 6.0f * (xv[2] - 2.0f * xv[1] + xv[0]);
    cp[1] = 0.25f;
    dp[1] = rhs * 0.25f;
#pragma unroll
    for (int i = 2; i <= 14; ++i) {
      rhs = 6.0f * (xv[i + 1] - 2.0f * xv[i] + xv[i - 1]);
      float m = 1.0f / (4.0f - cp[i - 1]);
      cp[i] = m;
      dp[i] = (rhs - dp[i - 1]) * m;
    }
    M[0] = 0.0f; M[15] = 0.0f;
    M[14] = dp[14];
#pragma unroll
    for (int i = 13; i >= 1; --i) M[i] = dp[i] - cp[i] * M[i + 1];
  }

#pragma unroll
  for (int p = 0; p < NPTS; ++p) {
    int i; float u;
    if (p < 45) { i = p / 3; u = (float)(p % 3) * (1.0f / 3.0f); }
    else        { i = 14;    u = 1.0f; }
    float b = (xv[i + 1] - xv[i]) - (2.0f * M[i] + M[i + 1]) * (1.0f / 6.0f);
    dX[p * (N_AG * D_IN) + idx] = b + M[i] * u + (M[i + 1] - M[i]) * (u * u * 0.5f);
  }
}

// One FC slice: rows 0..7 x (KS*32) @ W-tile columns ct = w + (tbase+t)*16.
// RELU=true: relu -> swizzled bf16 store. RELU=false: tanh -> same store (to G).
template <int KS, int NT, bool RELU>
__device__ __forceinline__ void fc(const ushort* __restrict__ Ain, int arowb,
                                   const ushort* __restrict__ Wp,
                                   const float* __restrict__ bias_lds,
                                   ushort* __restrict__ Outb, int orowb,
                                   int w, int lane, int tbase) {
  f32x4 acc[NT];
#pragma unroll
  for (int t = 0; t < NT; ++t) acc[t] = (f32x4){0.f, 0.f, 0.f, 0.f};

  const int row8 = lane & 7;
  const int g    = lane >> 4;
  const char* abase = (const char*)Ain + row8 * arowb;
  const int aswz = row8 << 4;

#pragma unroll 4
  for (int ks = 0; ks < KS; ++ks) {
    s16x8 a = *(const s16x8*)(abase + (((ks << 6) + (g << 4)) ^ aswz));
#pragma unroll
    for (int t = 0; t < NT; ++t) {
      int ct = w + ((tbase + t) << 4);
      s16x8 b = *(const s16x8*)(Wp + (((ct * KS + ks) * 64 + lane) << 3));
      acc[t] = __builtin_amdgcn_mfma_f32_16x16x32_bf16(a, b, acc[t], 0, 0, 0);
    }
  }

#pragma unroll
  for (int t = 0; t < NT; ++t) {
    int ct  = w + ((tbase + t) << 4);
    int col = (ct << 4) + (lane & 15);
    float bb = bias_lds[col];
#pragma unroll
    for (int r = 0; r < 4; ++r) {
      int orow = (g << 2) + r;
      if (orow < RROWS) {              // rows 8..15 dup of 0..7: skip
        float v = acc[t][r] + bb;
        if (RELU) v = fmaxf(v, 0.f);
        else      v = 1.0f - 2.0f * __builtin_amdgcn_rcpf(__expf(2.0f * v) + 1.0f);
        int byte = (orow * orowb + (col << 1)) ^ (orow << 4);
        *(ushort*)((char*)Outb + byte) = f2bf(v);
      }
    }
  }
}

__global__ __launch_bounds__(1024, 4) void cde_mfma(
    const float* __restrict__ x, const int* __restrict__ mask,
    const float* __restrict__ We, const float* __restrict__ be,
    const float* __restrict__ b0, const float* __restrict__ b1,
    const float* __restrict__ b2, const float* __restrict__ b3,
    const ushort* __restrict__ Wp, const float* __restrict__ dX,
    float* __restrict__ out) {
  const int tid  = threadIdx.x;
  const int lane = tid & 63;
  const int w    = tid >> 6;          // wave 0..15
  const int n0   = blockIdx.x * RROWS;

  __shared__ ushort A0[RROWS * 128];   // 2 KB  (z / zin, swizzled bf16)
  __shared__ ushort H1[RROWS * 512];   // 8 KB
  __shared__ ushort H2[RROWS * 512];   // 8 KB
  __shared__ ushort G[RROWS * 1280];   // 20 KB (tanh out, swizzled bf16)
  __shared__ float  BL[2816];          // b0|b1|b2|b3
  __shared__ float  dXs[RROWS][D_IN];

  float zreg, k1r, k2r, k3r;

  // biases -> LDS (once)
  if (tid < 512) {
    BL[tid] = b0[tid]; BL[512 + tid] = b1[tid]; BL[1024 + tid] = b2[tid];
  }
  BL[1536 + tid] = b3[tid];
  if (tid < 256) BL[2560 + tid] = b3[1024 + tid];

  // z0 = x[:,0,:] @ We^T + be   (1 (row,e) element per thread)
  const int e   = tid & 127;
  const int row = tid >> 7;
  {
    float acc = be[e];
    const float* xr = x + (n0 + row) * 160;
#pragma unroll
    for (int d = 0; d < 10; ++d) acc = fmaf(xr[d], We[e * 10 + d], acc);
    zreg = acc;
    int byte = ((row << 8) + (e << 1)) ^ (row << 4);
    *(ushort*)((char*)A0 + byte) = f2bf(acc);
  }
  __syncthreads();

#pragma unroll 1
  for (int s = 0; s < 15; ++s) {
#pragma unroll 1
    for (int st = 0; st < 4; ++st) {
      if (tid < RROWS * D_IN) {
        int p = (st < 3) ? (3 * s + st) : ((s < 14) ? (3 * s + 3) : 45);
        dXs[tid / 10][tid % 10] = dX[p * (N_AG * D_IN) + n0 * 10 + tid];
      }
      fc<4, 2, true>(A0, 256, Wp + OFF_W0P, BL, H1, 1024, w, lane, 0);
      __syncthreads();
      fc<16, 2, true>(H1, 1024, Wp + OFF_W1P, BL + 512, H2, 1024, w, lane, 0);
      __syncthreads();
      fc<16, 2, true>(H2, 1024, Wp + OFF_W2P, BL + 1024, H1, 1024, w, lane, 0);
      __syncthreads();
      fc<16, 3, false>(H1, 1024, Wp + OFF_W3P, BL + 1536, G, 2560, w, lane, 0);
      fc<16, 2, false>(H1, 1024, Wp + OFF_W3P, BL + 1536, G, 2560, w, lane, 3);
      __syncthreads();

      // contraction vf = sum_d G[row][e*10+d]*dXs[row][d]; RK4 (3/8), 1 elem/thread
      {
        float dv = 0.f;
#pragma unroll
        for (int d = 0; d < 10; ++d) {
          int byte = (row * 2560 + ((e * 10 + d) << 1)) ^ (row << 4);
          dv = fmaf(bf2f(*(const ushort*)((const char*)G + byte)), dXs[row][d], dv);
        }
        float z = zreg, zin;
        if (st == 0)      { k1r = dv; zin = z + dv * (1.f / 3.f); }
        else if (st == 1) { k2r = dv; zin = z + dv - k1r * (1.f / 3.f); }
        else if (st == 2) { k3r = dv; zin = z + k1r - k2r + dv; }
        else {
          z += (k1r + 3.f * (k2r + k3r) + dv) * 0.125f;
          zreg = z; zin = z;
        }
        int byte = ((row << 8) + (e << 1)) ^ (row << 4);
        *(ushort*)((char*)A0 + byte) = f2bf(zin);
      }
      __syncthreads();
    }
  }

  out[(n0 + row) * 128 + e] = (mask[n0 + row] != 0) ? zreg : 0.f;
}

extern "C" void kernel_launch(void* const* d_in, const int* in_sizes, int n_in,
                              void* d_out, int out_size, void* d_ws, size_t ws_size,
                              hipStream_t stream) {
  const float* x    = (const float*)d_in[1];
  const int*   mask = (const int*)d_in[2];
  const float* We   = (const float*)d_in[3];
  const float* be   = (const float*)d_in[4];
  const float* W0   = (const float*)d_in[5];
  const float* b0   = (const float*)d_in[6];
  const float* W1   = (const float*)d_in[7];
  const float* b1   = (const float*)d_in[8];
  const float* W2   = (const float*)d_in[9];
  const float* b2   = (const float*)d_in[10];
  const float* W3   = (const float*)d_in[11];
  const float* b3   = (const float*)d_in[12];
  float* out = (float*)d_out;

  ushort* wp = (ushort*)d_ws;
  float*  dX = (float*)((char*)d_ws + (size_t)OFF_END * 2);

  pack_w<<<(128 * 512 + 255) / 256, 256, 0, stream>>>(W0, wp + OFF_W0P, 512, 128);
  pack_w<<<(512 * 512 + 255) / 256, 256, 0, stream>>>(W1, wp + OFF_W1P, 512, 512);
  pack_w<<<(512 * 512 + 255) / 256, 256, 0, stream>>>(W2, wp + OFF_W2P, 512, 512);
  pack_w<<<(512 * 1280 + 255) / 256, 256, 0, stream>>>(W3, wp + OFF_W3P, 1280, 512);
  spline_dx_k<<<(N_AG * D_IN + 255) / 256, 256, 0, stream>>>(x, dX);
  cde_mfma<<<256, 1024, 0, stream>>>(x, mask, We, be, b0, b1, b2, b3, wp, dX, out);
}

// Round 7
// 2333.052 us; speedup vs baseline: 1.2972x; 1.2972x over previous
//
#include <hip/hip_runtime.h>
#include <hip/hip_bf16.h>

// Neural CDE forward, R7: R5 structure (512 thr / 8 waves / 8 rows / 256 blocks,
// proven spill-free) with per-wave ILP doubled: each mid layer is ONE fc call
// with NT=4 (8 B-fragment loads in flight, unroll 2) instead of two NT=2 calls.
// Layers via mfma_f32_16x16x32_bf16 with dup-row A (row = lane&7; C rows 8..15
// duplicate 0..7, skipped in epilogue). L3 fuses tanh + D-contraction via LDS
// atomicAdd into vf[8][128]. RK4 (3/8) state in registers.

typedef __attribute__((ext_vector_type(4))) float f32x4;
typedef __attribute__((ext_vector_type(8))) short s16x8;

#define N_AG  2048
#define D_IN  10
#define NPTS  46
#define RROWS 8

#define OFF_W0P 0
#define OFF_W1P (128 * 512)
#define OFF_W2P (OFF_W1P + 512 * 512)
#define OFF_W3P (OFF_W2P + 512 * 512)
#define OFF_END (OFF_W3P + 512 * 1280)   // ushorts

__device__ __forceinline__ ushort f2bf(float v) {
  __hip_bfloat16 h = __float2bfloat16(v);
  return *reinterpret_cast<ushort*>(&h);
}

// Pack W (O x K fp32, row-major) into MFMA B-fragment order (verified R2-R6):
// packed[((ct*KS+ks)*64 + lane)*8 + j] = bf16(W[col][k]),
// col = ct*16 + (lane&15), k = ks*32 + (lane>>4)*8 + j.
__global__ void pack_w(const float* __restrict__ W, ushort* __restrict__ Wp,
                       int O, int K) {
  int idx = blockIdx.x * blockDim.x + threadIdx.x;
  if (idx >= O * K) return;
  int j    = idx & 7;
  int lane = (idx >> 3) & 63;
  int rest = idx >> 9;
  int KS   = K >> 5;
  int ks   = rest % KS;
  int ct   = rest / KS;
  int col  = (ct << 4) + (lane & 15);
  int k    = (ks << 5) + ((lane >> 4) << 3) + j;
  Wp[idx]  = f2bf(W[col * K + k]);
}

// Natural cubic spline derivative table (verified R1-R6).
__global__ void spline_dx_k(const float* __restrict__ x, float* __restrict__ dX) {
  int idx = blockIdx.x * blockDim.x + threadIdx.x;
  if (idx >= N_AG * D_IN) return;
  int n = idx / D_IN;
  int d = idx - n * D_IN;

  float xv[16];
#pragma unroll
  for (int t = 0; t < 16; ++t) xv[t] = x[n * 160 + t * 10 + d];

  float cp[15], dp[15], M[16];
  {
    float rhs = 6.0f * (xv[2] - 2.0f * xv[1] + xv[0]);
    cp[1] = 0.25f;
    dp[1] = rhs * 0.25f;
#pragma unroll
    for (int i = 2; i <= 14; ++i) {
      rhs = 6.0f * (xv[i + 1] - 2.0f * xv[i] + xv[i - 1]);
      float m = 1.0f / (4.0f - cp[i - 1]);
      cp[i] = m;
      dp[i] = (rhs - dp[i - 1]) * m;
    }
    M[0] = 0.0f; M[15] = 0.0f;
    M[14] = dp[14];
#pragma unroll
    for (int i = 13; i >= 1; --i) M[i] = dp[i] - cp[i] * M[i + 1];
  }

#pragma unroll
  for (int p = 0; p < NPTS; ++p) {
    int i; float u;
    if (p < 45) { i = p / 3; u = (float)(p % 3) * (1.0f / 3.0f); }
    else        { i = 14;    u = 1.0f; }
    float b = (xv[i + 1] - xv[i]) - (2.0f * M[i] + M[i + 1]) * (1.0f / 6.0f);
    dX[p * (N_AG * D_IN) + idx] = b + M[i] * u + (M[i + 1] - M[i]) * (u * u * 0.5f);
  }
}

// One FC slice: rows 0..7 x (KS*32) @ W-tile columns ct = w + (tbase+t)*8.
// VF=false: relu -> swizzled bf16 store into Outb.
// VF=true : tanh -> vf[orow][col/10] += v * dXs[orow][col%10] (LDS atomic).
template <int KS, int NT, bool VF>
__device__ __forceinline__ void fc(const ushort* __restrict__ Ain, int arowb,
                                   const ushort* __restrict__ Wp,
                                   const float* __restrict__ bias_lds,
                                   ushort* __restrict__ Outb, int orowb,
                                   float (*__restrict__ vf)[128],
                                   const float (*__restrict__ dXs)[D_IN],
                                   int w, int lane, int tbase) {
  f32x4 acc[NT];
#pragma unroll
  for (int t = 0; t < NT; ++t) acc[t] = (f32x4){0.f, 0.f, 0.f, 0.f};

  const int row8 = lane & 7;
  const int g    = lane >> 4;
  const char* abase = (const char*)Ain + row8 * arowb;
  const int aswz = row8 << 4;

#pragma unroll 2
  for (int ks = 0; ks < KS; ++ks) {
    s16x8 a = *(const s16x8*)(abase + (((ks << 6) + (g << 4)) ^ aswz));
#pragma unroll
    for (int t = 0; t < NT; ++t) {
      int ct = w + ((tbase + t) << 3);
      s16x8 b = *(const s16x8*)(Wp + (((ct * KS + ks) * 64 + lane) << 3));
      acc[t] = __builtin_amdgcn_mfma_f32_16x16x32_bf16(a, b, acc[t], 0, 0, 0);
    }
  }

#pragma unroll
  for (int t = 0; t < NT; ++t) {
    int ct  = w + ((tbase + t) << 3);
    int col = (ct << 4) + (lane & 15);
    float bb = bias_lds[col];
#pragma unroll
    for (int r = 0; r < 4; ++r) {
      int orow = (g << 2) + r;
      if (orow < RROWS) {              // rows 8..15 are dup of 0..7: skip
        float v = acc[t][r] + bb;
        if (!VF) {
          v = fmaxf(v, 0.f);
          int byte = (orow * orowb + (col << 1)) ^ (orow << 4);
          *(ushort*)((char*)Outb + byte) = f2bf(v);
        } else {
          v = 1.0f - 2.0f * __builtin_amdgcn_rcpf(__expf(2.0f * v) + 1.0f);
          int e = col / 10, d = col - e * 10;
          atomicAdd(&vf[orow][e], v * dXs[orow][d]);
        }
      }
    }
  }
}

__global__ __launch_bounds__(512, 2) void cde_mfma(
    const float* __restrict__ x, const int* __restrict__ mask,
    const float* __restrict__ We, const float* __restrict__ be,
    const float* __restrict__ b0, const float* __restrict__ b1,
    const float* __restrict__ b2, const float* __restrict__ b3,
    const ushort* __restrict__ Wp, const float* __restrict__ dX,
    float* __restrict__ out) {
  const int tid  = threadIdx.x;
  const int lane = tid & 63;
  const int w    = tid >> 6;
  const int n0   = blockIdx.x * RROWS;

  __shared__ ushort A0[RROWS * 128];   // 2 KB, swizzled bf16
  __shared__ ushort H1[RROWS * 512];   // 8 KB
  __shared__ ushort H2[RROWS * 512];   // 8 KB
  __shared__ float  BL[2816];          // b0|b1|b2|b3
  __shared__ float  vf[RROWS][128];    // fused contraction accumulator
  __shared__ float  dXs[RROWS][D_IN];

  float zreg[2], k1r[2], k2r[2], k3r[2];

  // biases -> LDS (once)
  {
    int i = tid;
    BL[i] = b0[i]; BL[512 + i] = b1[i]; BL[1024 + i] = b2[i];
    BL[1536 + i] = b3[i];
    BL[2048 + i] = b3[512 + i];
    if (tid < 256) BL[2560 + tid] = b3[1024 + tid];
  }

  // z0 = x[:,0,:] @ We^T + be   (2 (row,e) elements per thread)
#pragma unroll
  for (int q = 0; q < 2; ++q) {
    int idx = (q << 9) + tid;
    int e = idx & 127, row = idx >> 7;
    float acc = be[e];
    const float* xr = x + (n0 + row) * 160;
#pragma unroll
    for (int d = 0; d < 10; ++d) acc = fmaf(xr[d], We[e * 10 + d], acc);
    zreg[q] = acc;
    int byte = ((row << 8) + (e << 1)) ^ (row << 4);
    *(ushort*)((char*)A0 + byte) = f2bf(acc);
  }
  __syncthreads();

#pragma unroll 1
  for (int s = 0; s < 15; ++s) {
#pragma unroll 1
    for (int st = 0; st < 4; ++st) {
      if (tid < RROWS * D_IN) {
        int p = (st < 3) ? (3 * s + st) : ((s < 14) ? (3 * s + 3) : 45);
        dXs[tid / 10][tid % 10] = dX[p * (N_AG * D_IN) + n0 * 10 + tid];
      }
      fc<4, 4, false>(A0, 256, Wp + OFF_W0P, BL, H1, 1024, vf, dXs, w, lane, 0);
      __syncthreads();
      fc<16, 4, false>(H1, 1024, Wp + OFF_W1P, BL + 512, H2, 1024, vf, dXs, w, lane, 0);
      __syncthreads();
      fc<16, 4, false>(H2, 1024, Wp + OFF_W2P, BL + 1024, H1, 1024, vf, dXs, w, lane, 0);
      // zero vf for this stage's contraction (disjoint; synced below)
      ((float*)vf)[tid] = 0.f;
      ((float*)vf)[512 + tid] = 0.f;
      __syncthreads();
      fc<16, 5, true>(H1, 1024, Wp + OFF_W3P, BL + 1536, nullptr, 0, vf, dXs, w, lane, 0);
      fc<16, 5, true>(H1, 1024, Wp + OFF_W3P, BL + 1536, nullptr, 0, vf, dXs, w, lane, 5);
      __syncthreads();

      // RK4 (3/8 rule), state in registers
#pragma unroll
      for (int q = 0; q < 2; ++q) {
        int idx = (q << 9) + tid;
        int e = idx & 127, row = idx >> 7;
        float dv = vf[row][e];
        float z = zreg[q], zin;
        if (st == 0)      { k1r[q] = dv; zin = z + dv * (1.f / 3.f); }
        else if (st == 1) { k2r[q] = dv; zin = z + dv - k1r[q] * (1.f / 3.f); }
        else if (st == 2) { k3r[q] = dv; zin = z + k1r[q] - k2r[q] + dv; }
        else {
          z += (k1r[q] + 3.f * (k2r[q] + k3r[q]) + dv) * 0.125f;
          zreg[q] = z; zin = z;
        }
        int byte = ((row << 8) + (e << 1)) ^ (row << 4);
        *(ushort*)((char*)A0 + byte) = f2bf(zin);
      }
      __syncthreads();
    }
  }

#pragma unroll
  for (int q = 0; q < 2; ++q) {
    int idx = (q << 9) + tid;
    int e = idx & 127, row = idx >> 7;
    out[(n0 + row) * 128 + e] = (mask[n0 + row] != 0) ? zreg[q] : 0.f;
  }
}

extern "C" void kernel_launch(void* const* d_in, const int* in_sizes, int n_in,
                              void* d_out, int out_size, void* d_ws, size_t ws_size,
                              hipStream_t stream) {
  const float* x    = (const float*)d_in[1];
  const int*   mask = (const int*)d_in[2];
  const float* We   = (const float*)d_in[3];
  const float* be   = (const float*)d_in[4];
  const float* W0   = (const float*)d_in[5];
  const float* b0   = (const float*)d_in[6];
  const float* W1   = (const float*)d_in[7];
  const float* b1   = (const float*)d_in[8];
  const float* W2   = (const float*)d_in[9];
  const float* b2   = (const float*)d_in[10];
  const float* W3   = (const float*)d_in[11];
  const float* b3   = (const float*)d_in[12];
  float* out = (float*)d_out;

  ushort* wp = (ushort*)d_ws;
  float*  dX = (float*)((char*)d_ws + (size_t)OFF_END * 2);

  pack_w<<<(128 * 512 + 255) / 256, 256, 0, stream>>>(W0, wp + OFF_W0P, 512, 128);
  pack_w<<<(512 * 512 + 255) / 256, 256, 0, stream>>>(W1, wp + OFF_W1P, 512, 512);
  pack_w<<<(512 * 512 + 255) / 256, 256, 0, stream>>>(W2, wp + OFF_W2P, 512, 512);
  pack_w<<<(512 * 1280 + 255) / 256, 256, 0, stream>>>(W3, wp + OFF_W3P, 1280, 512);
  spline_dx_k<<<(N_AG * D_IN + 255) / 256, 256, 0, stream>>>(x, dX);
  cde_mfma<<<256, 512, 0, stream>>>(x, mask, We, be, b0, b1, b2, b3, wp, dX, out);
}